// Round 4
// baseline (165.604 us; speedup 1.0000x reference)
//
#include <hip/hip_runtime.h>
#include <hip/hip_bf16.h>

typedef __attribute__((ext_vector_type(8))) short bf16x8;
typedef __attribute__((ext_vector_type(4))) float f32x4;

#define D128 128
#define TILE_M 256
#define IMG_SHORTS 16384          // one W frag-image: 32 frags x 64 lanes x 8 bf16 = 32 KB
#define XB_OFF (131072 / 2)       // xb at 128 KiB into d_ws (in shorts)

__device__ __forceinline__ short f2bf(float f) {
    union { float f; unsigned u; } v; v.f = f;
    unsigned r = (v.u + 0x7FFFu + ((v.u >> 16) & 1u)) >> 16;  // RNE
    return (short)r;
}

__device__ __forceinline__ short f2bf_h(float f) {
    __hip_bfloat16 h = __float2bfloat16(f);
    short s;
    __builtin_memcpy(&s, &h, sizeof(short));
    return s;
}

__device__ __forceinline__ bf16x8 pack8(float4 a, float4 b) {
    bf16x8 r;
    r[0] = f2bf_h(a.x); r[1] = f2bf_h(a.y); r[2] = f2bf_h(a.z); r[3] = f2bf_h(a.w);
    r[4] = f2bf_h(b.x); r[5] = f2bf_h(b.y); r[6] = f2bf_h(b.z); r[7] = f2bf_h(b.w);
    return r;
}

__device__ __forceinline__ void gload_lds16(const short* g, short* l) {
    __builtin_amdgcn_global_load_lds(
        (const __attribute__((address_space(1))) unsigned int*)(const void*)g,
        (__attribute__((address_space(3))) unsigned int*)(void*)l, 16, 0, 0);
}

// W (3*128 x 128 fp32 row-major) -> 3 A-operand fragment images:
// img[c][frag=mt*4+ks][lane][j] = W[c*128 + ks*32 + (lane>>4)*8 + j][mt*16 + (lane&15)]
// Grid: 24 blocks x 256 thr; thread = (c, frag, lane).
__global__ __launch_bounds__(256) void wt_kernel(const float* __restrict__ W,
                                                 short* __restrict__ Wimg) {
    const int c    = blockIdx.x >> 3;
    const int frag = (blockIdx.x & 7) * 4 + (threadIdx.x >> 6);
    const int lane = threadIdx.x & 63;
    const int mt = frag >> 2, ks = frag & 3;
    const int m  = mt * 16 + (lane & 15);
    const int k0 = ks * 32 + (lane >> 4) * 8;
    bf16x8 v;
#pragma unroll
    for (int j = 0; j < 8; ++j)
        v[j] = f2bf(W[(size_t)(c * 128 + k0 + j) * D128 + m]);
    *reinterpret_cast<bf16x8*>(
        &Wimg[((size_t)c * 32 + frag) * 64 * 8 + (size_t)lane * 8]) = v;
}

// x (fp32) -> xb (bf16), 8 elems/thread.
__global__ __launch_bounds__(256) void xb_kernel(const float* __restrict__ x,
                                                 short* __restrict__ xb) {
    const size_t i = ((size_t)blockIdx.x * 256 + threadIdx.x) * 8;
    float4 v0 = reinterpret_cast<const float4*>(x + i)[0];
    float4 v1 = reinterpret_cast<const float4*>(x + i)[1];
    *reinterpret_cast<bf16x8*>(xb + i) = pack8(v0, v1);
}

// Fused gather-GEMM, one barrier, swapped MFMA operands:
// out[r] = [x[src[r]] | x[dst[r]] | e[r]] @ W  (bf16 MFMA, fp32 acc)
// 1024 thr = 16 waves; lane owns one output row rn = r0 + w*16 + (lane&15).
__global__ __launch_bounds__(1024, 4) void fused_kernel(
        const short* __restrict__ xb,
        const float* __restrict__ e,
        const short* __restrict__ Wimg,
        const int*  __restrict__ src_idx,
        const int*  __restrict__ dst_idx,
        float* __restrict__ out,
        int E)
{
    __shared__ short Ws[3 * IMG_SHORTS];   // 96 KB, 3 frag images

    const int tid  = threadIdx.x;
    const int lane = tid & 63;
    const int w    = tid >> 6;            // 0..15
    const int lhi  = lane >> 4;           // 0..3
    const int r0   = blockIdx.x * TILE_M;
    const int rn   = r0 + w * 16 + (lane & 15);
    const bool valid = rn < E;
    const int  rl  = valid ? rn : (E - 1);

    // ---- idx first (oldest vm ops after... actually issued before stage) ----
    const int si = src_idx[rl];
    const int di = dst_idx[rl];
    asm volatile("" ::: "memory");   // pin: idx before stage

    // ---- stage 3 W images: 6144 x 16B units, 6 per lane, linear both sides ----
#pragma unroll
    for (int jj = 0; jj < 6; ++jj) {
        int unit = jj * 1024 + tid;
        gload_lds16(Wimg + (size_t)unit * 8, &Ws[unit * 8]);
    }
    asm volatile("" ::: "memory");   // pin: stage before gathers

    // ---- issue all gathers + e loads (16 x 16B per lane), stay in flight ----
    const short* ps = xb + (size_t)si * D128;
    const short* pd = xb + (size_t)di * D128;
    const float* pe = e + (size_t)rl * D128;
    bf16x8 bs[4], bd[4];
    float4 ev[8];
#pragma unroll
    for (int ks = 0; ks < 4; ++ks) {
        bs[ks] = *reinterpret_cast<const bf16x8*>(ps + ks * 32 + lhi * 8);
        bd[ks] = *reinterpret_cast<const bf16x8*>(pd + ks * 32 + lhi * 8);
        ev[2 * ks]     = reinterpret_cast<const float4*>(pe + ks * 32 + lhi * 8)[0];
        ev[2 * ks + 1] = reinterpret_cast<const float4*>(pe + ks * 32 + lhi * 8)[1];
    }
    asm volatile("" ::: "memory");
    // Drain the 6 stage DMAs (older than the 16 loads above); gathers keep flying.
    asm volatile("s_waitcnt vmcnt(16)" ::: "memory");
    __builtin_amdgcn_s_barrier();

    f32x4 acc[8];
#pragma unroll
    for (int mt = 0; mt < 8; ++mt) acc[mt] = (f32x4){0.f, 0.f, 0.f, 0.f};

    // ---- chunk 0 (src), chunk 1 (dst): bf16 gathers consumed directly ----
#pragma unroll
    for (int ks = 0; ks < 4; ++ks)
#pragma unroll
        for (int mt = 0; mt < 8; ++mt) {
            bf16x8 a = *reinterpret_cast<const bf16x8*>(
                &Ws[((0 * 32 + mt * 4 + ks) * 64 + lane) * 8]);
            acc[mt] = __builtin_amdgcn_mfma_f32_16x16x32_bf16(a, bs[ks], acc[mt], 0, 0, 0);
        }
#pragma unroll
    for (int ks = 0; ks < 4; ++ks)
#pragma unroll
        for (int mt = 0; mt < 8; ++mt) {
            bf16x8 a = *reinterpret_cast<const bf16x8*>(
                &Ws[((1 * 32 + mt * 4 + ks) * 64 + lane) * 8]);
            acc[mt] = __builtin_amdgcn_mfma_f32_16x16x32_bf16(a, bd[ks], acc[mt], 0, 0, 0);
        }

    // ---- chunk 2 (e): convert then MFMA ----
    bf16x8 be[4];
#pragma unroll
    for (int ks = 0; ks < 4; ++ks) be[ks] = pack8(ev[2 * ks], ev[2 * ks + 1]);
#pragma unroll
    for (int ks = 0; ks < 4; ++ks)
#pragma unroll
        for (int mt = 0; mt < 8; ++mt) {
            bf16x8 a = *reinterpret_cast<const bf16x8*>(
                &Ws[((2 * 32 + mt * 4 + ks) * 64 + lane) * 8]);
            acc[mt] = __builtin_amdgcn_mfma_f32_16x16x32_bf16(a, be[ks], acc[mt], 0, 0, 0);
        }

    // ---- epilogue: lane holds out[rn][mt*16 + lhi*4 .. +3] -> dwordx4 stores ----
    if (valid) {
        float* po = out + (size_t)rn * D128 + lhi * 4;
#pragma unroll
        for (int mt = 0; mt < 8; ++mt)
            *reinterpret_cast<float4*>(po + mt * 16) = *(float4*)&acc[mt];
    }
}

extern "C" void kernel_launch(void* const* d_in, const int* in_sizes, int n_in,
                              void* d_out, int out_size, void* d_ws, size_t ws_size,
                              hipStream_t stream) {
    const float* x = (const float*)d_in[0];
    const float* e = (const float*)d_in[1];
    const float* W = (const float*)d_in[2];
    const int* src = (const int*)d_in[3];
    const int* dst = (const int*)d_in[4];
    float* out = (float*)d_out;

    short* Wimg = (short*)d_ws;                 // 3 x 32 KB frag images
    short* xb   = (short*)d_ws + XB_OFF;        // 100000*128 bf16 = 25.6 MB

    const int N = in_sizes[0] / D128;           // 100000
    const int E = in_sizes[3];                  // 400000
    const int blocks = (E + TILE_M - 1) / TILE_M;   // 1563

    wt_kernel<<<24, 256, 0, stream>>>(W, Wimg);
    xb_kernel<<<(N * D128) / (256 * 8), 256, 0, stream>>>(x, xb);
    fused_kernel<<<blocks, 1024, 0, stream>>>(xb, e, Wimg, src, dst, out, E);
}